// Round 2
// baseline (659.879 us; speedup 1.0000x reference)
//
#include <hip/hip_runtime.h>

#define EPS_BN 1e-5f

// 3-NN + inverse-distance weights. Per-b (xyz broadcast across Q).
// Explicit rn ops match numpy's non-contracted fp32 ((dx^2+dy^2)+dz^2);
// strict < keeps lower index on ties (matches stable top_k).
__global__ __launch_bounds__(256) void three_nn_kernel(
    const float* __restrict__ unknown,  // (B, Nu, 3)
    const float* __restrict__ known,    // (B, Nk, 3)
    int Nu, int Nk, int* __restrict__ idx, float* __restrict__ wgt)
{
    __shared__ float kl[3 * 1024];
    int b = blockIdx.y;
    for (int i = threadIdx.x; i < Nk * 3; i += 256) kl[i] = known[(size_t)b * Nk * 3 + i];
    __syncthreads();
    int n = blockIdx.x * 256 + threadIdx.x;
    if (n >= Nu) return;
    const float* up = unknown + ((size_t)b * Nu + n) * 3;
    float ux = up[0], uy = up[1], uz = up[2];
    float d0 = 1e30f, d1 = 1e30f, d2 = 1e30f;
    int i0 = 0, i1 = 0, i2 = 0;
    for (int k = 0; k < Nk; ++k) {
        float dx = __fsub_rn(ux, kl[3 * k + 0]);
        float dy = __fsub_rn(uy, kl[3 * k + 1]);
        float dz = __fsub_rn(uz, kl[3 * k + 2]);
        float d = __fadd_rn(__fadd_rn(__fmul_rn(dx, dx), __fmul_rn(dy, dy)), __fmul_rn(dz, dz));
        if (d < d0)      { d2 = d1; i2 = i1; d1 = d0; i1 = i0; d0 = d; i0 = k; }
        else if (d < d1) { d2 = d1; i2 = i1; d1 = d;  i1 = k; }
        else if (d < d2) { d2 = d;  i2 = k; }
    }
    float w0 = 1.f / (d0 + 1e-8f), w1 = 1.f / (d1 + 1e-8f), w2 = 1.f / (d2 + 1e-8f);
    float s = w0 + w1 + w2;
    size_t base = ((size_t)b * Nu + n) * 3;
    idx[base + 0] = i0; idx[base + 1] = i1; idx[base + 2] = i2;
    wgt[base + 0] = w0 / s; wgt[base + 1] = w1 / s; wgt[base + 2] = w2 / s;
}

__global__ void interp_kernel(const float* __restrict__ feat,  // (NB, C, Ns)
    const int* __restrict__ idx, const float* __restrict__ wgt, // (B, Nu, 3)
    float* __restrict__ out,                                    // (NB, C, Nu)
    int C, int Ns, int Nu, int Q)
{
    int n = blockIdx.x * 256 + threadIdx.x;
    if (n >= Nu) return;
    int c = blockIdx.y;
    int nb = blockIdx.z;
    int b = nb / Q;
    size_t nnb = ((size_t)b * Nu + n) * 3;
    int j0 = idx[nnb], j1 = idx[nnb + 1], j2 = idx[nnb + 2];
    float w0 = wgt[nnb], w1 = wgt[nnb + 1], w2 = wgt[nnb + 2];
    const float* f = feat + ((size_t)nb * C + c) * Ns;
    out[((size_t)nb * C + c) * Nu + n] = w0 * f[j0] + w1 * f[j1] + w2 * f[j2];
}

// out(NB,O,N) = act(bn(W @ concat(src0, src1) + bias))
// Block: 16 o x 256 n; thread: 4o x 4n; K-tile 32 staged in LDS.
__global__ __launch_bounds__(256) void conv_bn_relu_kernel(
    const float* __restrict__ src0, int C0, int qdiv0,
    const float* __restrict__ src1, int C1, int qdiv1,
    const float* __restrict__ W, const float* __restrict__ bias,
    const float* __restrict__ bn,
    float* __restrict__ outp,
    int O, int N, int relu)
{
    __shared__ __align__(16) float wlds[304 * 16];   // [c][16 o_local]
    __shared__ __align__(16) float xlds[32 * 256];   // [c][256 n_local]
    const int tx = threadIdx.x, ty = threadIdx.y;
    const int tid = ty * 64 + tx;
    const int nBase = blockIdx.x * 256;
    const int oBase = blockIdx.y * 16;
    const int nb = blockIdx.z;
    const int Ctot = C0 + C1;

    for (int i = tid; i < Ctot * 16; i += 256) {
        int c = i >> 4, ol = i & 15;
        int o = oBase + ol;
        wlds[i] = (o < O) ? W[(size_t)o * Ctot + c] : 0.f;
    }

    const float* s0 = src0 + (size_t)(nb / qdiv0) * C0 * N;
    const float* s1 = (C1 > 0) ? (src1 + (size_t)(nb / qdiv1) * C1 * N) : nullptr;

    float acc[4][4];
#pragma unroll
    for (int a = 0; a < 4; ++a)
#pragma unroll
        for (int b2 = 0; b2 < 4; ++b2) acc[a][b2] = 0.f;

    for (int c0 = 0; c0 < Ctot; c0 += 32) {
        __syncthreads();
        for (int i = tid; i < 2048; i += 256) {
            int c = i >> 6;
            int n4 = (i & 63) << 2;
            int cg = c0 + c;
            float4 v = make_float4(0.f, 0.f, 0.f, 0.f);
            if (cg < C0)        v = *reinterpret_cast<const float4*>(s0 + (size_t)cg * N + nBase + n4);
            else if (cg < Ctot) v = *reinterpret_cast<const float4*>(s1 + (size_t)(cg - C0) * N + nBase + n4);
            *reinterpret_cast<float4*>(&xlds[c * 256 + n4]) = v;
        }
        __syncthreads();
        const int kmax = (Ctot - c0) < 32 ? (Ctot - c0) : 32;
        if (kmax == 32) {
#pragma unroll 4
            for (int k = 0; k < 32; ++k) {
                float4 xv = *reinterpret_cast<const float4*>(&xlds[k * 256 + (tx << 2)]);
                float4 wv = *reinterpret_cast<const float4*>(&wlds[(c0 + k) * 16 + (ty << 2)]);
                float xr[4] = {xv.x, xv.y, xv.z, xv.w};
                float wr[4] = {wv.x, wv.y, wv.z, wv.w};
#pragma unroll
                for (int a = 0; a < 4; ++a)
#pragma unroll
                    for (int b2 = 0; b2 < 4; ++b2) acc[a][b2] += wr[a] * xr[b2];
            }
        } else {
            for (int k = 0; k < kmax; ++k) {
                float4 xv = *reinterpret_cast<const float4*>(&xlds[k * 256 + (tx << 2)]);
                float4 wv = *reinterpret_cast<const float4*>(&wlds[(c0 + k) * 16 + (ty << 2)]);
                float xr[4] = {xv.x, xv.y, xv.z, xv.w};
                float wr[4] = {wv.x, wv.y, wv.z, wv.w};
#pragma unroll
                for (int a = 0; a < 4; ++a)
#pragma unroll
                    for (int b2 = 0; b2 < 4; ++b2) acc[a][b2] += wr[a] * xr[b2];
            }
        }
    }

#pragma unroll
    for (int a = 0; a < 4; ++a) {
        int o = oBase + ty * 4 + a;
        if (o >= O) continue;
        float bval = bias[o];
        float scale = 1.f, shift = 0.f;
        if (bn) {
            float g  = bn[o];
            float be = bn[O + o];
            float m  = bn[2 * O + o];
            float v  = bn[3 * O + o];
            scale = g * rsqrtf(v + EPS_BN);
            shift = be - m * scale;
        }
        size_t rowOff = ((size_t)nb * O + o) * N + nBase + tx * 4;
#pragma unroll
        for (int b2 = 0; b2 < 4; ++b2) {
            float y = (acc[a][b2] + bval) * scale + shift;
            if (relu) y = fmaxf(y, 0.f);
            outp[rowOff + b2] = y;
        }
    }
}

extern "C" void kernel_launch(void* const* d_in, const int* in_sizes, int n_in,
                              void* d_out, int out_size, void* d_ws, size_t ws_size,
                              hipStream_t stream) {
    const int B = 2, Q = 16, N0 = 4096, N1 = 1024, N2 = 256;
    const int I1 = 144, I2 = 72, I3 = 36;
    const int NB = B * Q;  // 32

    const float* x     = (const float*)d_in[0];   // (B, 288, N2)
    const float* mask  = (const float*)d_in[1];   // (NB, 8, N2)
    const float* sa0f  = (const float*)d_in[2];   // (B, 3, N0)
    const float* sa1f  = (const float*)d_in[3];   // (B, 128, N1)
    const float* xyz0  = (const float*)d_in[4];   // (B, N0, 3)
    const float* xyz1  = (const float*)d_in[5];   // (B, N1, 3)
    const float* xyz2  = (const float*)d_in[6];   // (B, N2, 3)

    float* ws = (float*)d_ws;
    size_t off = 0;
    auto alloc = [&](size_t n) { size_t p = off; off += (n + 15) & ~(size_t)15; return p; };

    size_t f0b   = alloc((size_t)B * I2 * N0);    // adapter1 out (per-b)
    size_t f1b   = alloc((size_t)B * I1 * N1);    // adapter2 out (per-b)
    size_t wgt1  = alloc((size_t)B * N1 * 3);
    size_t wgt2  = alloc((size_t)B * N0 * 3);
    size_t idx1  = alloc((size_t)B * N1 * 3);
    size_t idx2  = alloc((size_t)B * N0 * 3);
    size_t slotA = alloc((size_t)NB * I2 * N0);   // h1 / interp1 / interp2
    size_t slotB = alloc((size_t)NB * I2 * N0);   // h2 / h3 / h5
    size_t slotC = alloc((size_t)NB * I3 * N0);   // h4 / h6
    (void)ws_size; (void)in_sizes; (void)n_in;

    auto conv = [&](const float* s0, int C0, int q0, const float* s1, int C1, int q1,
                    int wi, int bi, int bni, float* outp,
                    int O, int Nn, int nbatch, int relu) {
        dim3 grid((Nn + 255) / 256, (O + 15) / 16, nbatch);
        conv_bn_relu_kernel<<<grid, dim3(64, 4), 0, stream>>>(
            s0, C0, q0, s1, C1, q1,
            (const float*)d_in[wi], (const float*)d_in[bi],
            bni >= 0 ? (const float*)d_in[bni] : nullptr,
            outp, O, Nn, relu);
    };

    // adapters (per-b)
    conv(sa0f, 3, 1, nullptr, 0, 1, 13, 14, -1, ws + f0b, I2, N0, B, 0);
    conv(sa1f, 128, 1, nullptr, 0, 1, 15, 16, -1, ws + f1b, I1, N1, B, 0);

    // three_nn (per-b)
    three_nn_kernel<<<dim3(N1 / 256, B), dim3(256), 0, stream>>>(
        xyz1, xyz2, N1, N2, (int*)(ws + idx1), ws + wgt1);
    three_nn_kernel<<<dim3(N0 / 256, B), dim3(256), 0, stream>>>(
        xyz0, xyz1, N0, N1, (int*)(ws + idx2), ws + wgt2);

    // h1 = layer1(concat(x, mask)) : (NB, 296, 256) -> slotA
    conv(x, 288, Q, mask, 8, 1, 7, 8, 9, ws + slotA, 296, N2, NB, 1);
    // h2 = layer2(h1) : (NB, 144, 256) -> slotB
    conv(ws + slotA, 296, 1, nullptr, 0, 1, 10, 11, 12, ws + slotB, I1, N2, NB, 1);

    // interp1: h2 (Ns=256) -> (NB, 144, 1024) -> slotA
    interp_kernel<<<dim3(N1 / 256, I1, NB), dim3(256), 0, stream>>>(
        ws + slotB, (const int*)(ws + idx1), ws + wgt1, ws + slotA, I1, N2, N1, Q);

    // h3 = fp1_layer1(concat(interp1, f1)) -> slotB
    conv(ws + slotA, I1, 1, ws + f1b, I1, Q, 17, 18, 19, ws + slotB, I1, N1, NB, 1);
    // h4 = fp1_layer2(h3) -> slotC
    conv(ws + slotB, I1, 1, nullptr, 0, 1, 20, 21, 22, ws + slotC, I2, N1, NB, 1);

    // interp2: h4 (Ns=1024) -> (NB, 72, 4096) -> slotA
    interp_kernel<<<dim3(N0 / 256, I2, NB), dim3(256), 0, stream>>>(
        ws + slotC, (const int*)(ws + idx2), ws + wgt2, ws + slotA, I2, N1, N0, Q);

    // h5 = fp2_layer1(concat(interp2, f0)) -> slotB
    conv(ws + slotA, I2, 1, ws + f0b, I2, Q, 23, 24, 25, ws + slotB, I2, N0, NB, 1);
    // h6 = fp2_layer2(h5) -> slotC
    conv(ws + slotB, I2, 1, nullptr, 0, 1, 26, 27, 28, ws + slotC, I3, N0, NB, 1);

    // out = out_w @ h6 + out_b -> d_out (fp32)
    conv(ws + slotC, I3, 1, nullptr, 0, 1, 29, 30, -1, (float*)d_out, 1, N0, NB, 0);
}

// Round 3
// 454.559 us; speedup vs baseline: 1.4517x; 1.4517x over previous
//
#include <hip/hip_runtime.h>

#define EPS_BN 1e-5f

// Segment-parallel 3-NN + inverse-distance weights. Per-b (xyz broadcast
// across Q). Block = 512 threads = 32 unknowns x 16 K-segments; per-thread
// top-3 over Nk/16 points, then 32 merge lanes fold 16x3 candidates in
// ascending segment order with strict < (preserves top_k lowest-index
// tie-break). Distances use explicit rn ops -> bit-identical to numpy fp32.
__global__ __launch_bounds__(512) void three_nn_par_kernel(
    const float* __restrict__ unknown,  // (B, Nu, 3)
    const float* __restrict__ known,    // (B, Nk, 3)
    int Nu, int Nk, int* __restrict__ idx, float* __restrict__ wgt)
{
    const int NSEG = 16;
    __shared__ float kl[3 * 1024];
    __shared__ float sd[NSEG][32][3];
    __shared__ int   si[NSEG][32][3];
    const int b = blockIdx.y;
    for (int i = threadIdx.x; i < Nk * 3; i += 512) kl[i] = known[(size_t)b * Nk * 3 + i];
    __syncthreads();
    const int u   = threadIdx.x & 31;
    const int seg = threadIdx.x >> 5;
    const int n   = blockIdx.x * 32 + u;   // Nu is a multiple of 32
    const float* up = unknown + ((size_t)b * Nu + n) * 3;
    const float ux = up[0], uy = up[1], uz = up[2];
    float d0 = 1e30f, d1 = 1e30f, d2 = 1e30f;
    int i0 = 0, i1 = 0, i2 = 0;
    const int klo = seg * (Nk / NSEG), khi = klo + Nk / NSEG;
    for (int k = klo; k < khi; ++k) {
        float dx = __fsub_rn(ux, kl[3 * k + 0]);
        float dy = __fsub_rn(uy, kl[3 * k + 1]);
        float dz = __fsub_rn(uz, kl[3 * k + 2]);
        float d = __fadd_rn(__fadd_rn(__fmul_rn(dx, dx), __fmul_rn(dy, dy)), __fmul_rn(dz, dz));
        if (d < d0)      { d2 = d1; i2 = i1; d1 = d0; i1 = i0; d0 = d; i0 = k; }
        else if (d < d1) { d2 = d1; i2 = i1; d1 = d;  i1 = k; }
        else if (d < d2) { d2 = d;  i2 = k; }
    }
    sd[seg][u][0] = d0; sd[seg][u][1] = d1; sd[seg][u][2] = d2;
    si[seg][u][0] = i0; si[seg][u][1] = i1; si[seg][u][2] = i2;
    __syncthreads();
    if (threadIdx.x < 32) {
        float m0 = 1e30f, m1 = 1e30f, m2 = 1e30f;
        int j0 = 0, j1 = 0, j2 = 0;
        for (int s = 0; s < NSEG; ++s)
            for (int c = 0; c < 3; ++c) {
                float d = sd[s][u][c];
                int ii = si[s][u][c];
                if (d < m0)      { m2 = m1; j2 = j1; m1 = m0; j1 = j0; m0 = d; j0 = ii; }
                else if (d < m1) { m2 = m1; j2 = j1; m1 = d;  j1 = ii; }
                else if (d < m2) { m2 = d;  j2 = ii; }
            }
        float w0 = 1.f / (m0 + 1e-8f), w1 = 1.f / (m1 + 1e-8f), w2 = 1.f / (m2 + 1e-8f);
        float s = w0 + w1 + w2;
        size_t base = ((size_t)b * Nu + n) * 3;
        idx[base + 0] = j0; idx[base + 1] = j1; idx[base + 2] = j2;
        wgt[base + 0] = w0 / s; wgt[base + 1] = w1 / s; wgt[base + 2] = w2 / s;
    }
}

__global__ void interp_kernel(const float* __restrict__ feat,  // (NB, C, Ns)
    const int* __restrict__ idx, const float* __restrict__ wgt, // (B, Nu, 3)
    float* __restrict__ out,                                    // (NB, C, Nu)
    int C, int Ns, int Nu, int Q)
{
    int n = blockIdx.x * 256 + threadIdx.x;
    if (n >= Nu) return;
    int c = blockIdx.y;
    int nb = blockIdx.z;
    int b = nb / Q;
    size_t nnb = ((size_t)b * Nu + n) * 3;
    int j0 = idx[nnb], j1 = idx[nnb + 1], j2 = idx[nnb + 2];
    float w0 = wgt[nnb], w1 = wgt[nnb + 1], w2 = wgt[nnb + 2];
    const float* f = feat + ((size_t)nb * C + c) * Ns;
    out[((size_t)nb * C + c) * Nu + n] = w0 * f[j0] + w1 * f[j1] + w2 * f[j2];
}

// out(NB,O,N) = act(bn(W @ concat(src0, src1) + bias))
// Block: 16 o x 256 n; thread: 4o x 4n; K-tile 32 staged in LDS.
__global__ __launch_bounds__(256) void conv_bn_relu_kernel(
    const float* __restrict__ src0, int C0, int qdiv0,
    const float* __restrict__ src1, int C1, int qdiv1,
    const float* __restrict__ W, const float* __restrict__ bias,
    const float* __restrict__ bn,
    float* __restrict__ outp,
    int O, int N, int relu)
{
    __shared__ __align__(16) float wlds[304 * 16];   // [c][16 o_local]
    __shared__ __align__(16) float xlds[32 * 256];   // [c][256 n_local]
    const int tx = threadIdx.x, ty = threadIdx.y;
    const int tid = ty * 64 + tx;
    const int nBase = blockIdx.x * 256;
    const int oBase = blockIdx.y * 16;
    const int nb = blockIdx.z;
    const int Ctot = C0 + C1;

    for (int i = tid; i < Ctot * 16; i += 256) {
        int c = i >> 4, ol = i & 15;
        int o = oBase + ol;
        wlds[i] = (o < O) ? W[(size_t)o * Ctot + c] : 0.f;
    }

    const float* s0 = src0 + (size_t)(nb / qdiv0) * C0 * N;
    const float* s1 = (C1 > 0) ? (src1 + (size_t)(nb / qdiv1) * C1 * N) : nullptr;

    float acc[4][4];
#pragma unroll
    for (int a = 0; a < 4; ++a)
#pragma unroll
        for (int b2 = 0; b2 < 4; ++b2) acc[a][b2] = 0.f;

    for (int c0 = 0; c0 < Ctot; c0 += 32) {
        __syncthreads();
        for (int i = tid; i < 2048; i += 256) {
            int c = i >> 6;
            int n4 = (i & 63) << 2;
            int cg = c0 + c;
            float4 v = make_float4(0.f, 0.f, 0.f, 0.f);
            if (cg < C0)        v = *reinterpret_cast<const float4*>(s0 + (size_t)cg * N + nBase + n4);
            else if (cg < Ctot) v = *reinterpret_cast<const float4*>(s1 + (size_t)(cg - C0) * N + nBase + n4);
            *reinterpret_cast<float4*>(&xlds[c * 256 + n4]) = v;
        }
        __syncthreads();
        const int kmax = (Ctot - c0) < 32 ? (Ctot - c0) : 32;
        if (kmax == 32) {
#pragma unroll 4
            for (int k = 0; k < 32; ++k) {
                float4 xv = *reinterpret_cast<const float4*>(&xlds[k * 256 + (tx << 2)]);
                float4 wv = *reinterpret_cast<const float4*>(&wlds[(c0 + k) * 16 + (ty << 2)]);
                float xr[4] = {xv.x, xv.y, xv.z, xv.w};
                float wr[4] = {wv.x, wv.y, wv.z, wv.w};
#pragma unroll
                for (int a = 0; a < 4; ++a)
#pragma unroll
                    for (int b2 = 0; b2 < 4; ++b2) acc[a][b2] += wr[a] * xr[b2];
            }
        } else {
            for (int k = 0; k < kmax; ++k) {
                float4 xv = *reinterpret_cast<const float4*>(&xlds[k * 256 + (tx << 2)]);
                float4 wv = *reinterpret_cast<const float4*>(&wlds[(c0 + k) * 16 + (ty << 2)]);
                float xr[4] = {xv.x, xv.y, xv.z, xv.w};
                float wr[4] = {wv.x, wv.y, wv.z, wv.w};
#pragma unroll
                for (int a = 0; a < 4; ++a)
#pragma unroll
                    for (int b2 = 0; b2 < 4; ++b2) acc[a][b2] += wr[a] * xr[b2];
            }
        }
    }

#pragma unroll
    for (int a = 0; a < 4; ++a) {
        int o = oBase + ty * 4 + a;
        if (o >= O) continue;
        float bval = bias[o];
        float scale = 1.f, shift = 0.f;
        if (bn) {
            float g  = bn[o];
            float be = bn[O + o];
            float m  = bn[2 * O + o];
            float v  = bn[3 * O + o];
            scale = g * rsqrtf(v + EPS_BN);
            shift = be - m * scale;
        }
        size_t rowOff = ((size_t)nb * O + o) * N + nBase + tx * 4;
#pragma unroll
        for (int b2 = 0; b2 < 4; ++b2) {
            float y = (acc[a][b2] + bval) * scale + shift;
            if (relu) y = fmaxf(y, 0.f);
            outp[rowOff + b2] = y;
        }
    }
}

extern "C" void kernel_launch(void* const* d_in, const int* in_sizes, int n_in,
                              void* d_out, int out_size, void* d_ws, size_t ws_size,
                              hipStream_t stream) {
    const int B = 2, Q = 16, N0 = 4096, N1 = 1024, N2 = 256;
    const int I1 = 144, I2 = 72, I3 = 36;
    const int NB = B * Q;  // 32

    const float* x     = (const float*)d_in[0];   // (B, 288, N2)
    const float* mask  = (const float*)d_in[1];   // (NB, 8, N2)
    const float* sa0f  = (const float*)d_in[2];   // (B, 3, N0)
    const float* sa1f  = (const float*)d_in[3];   // (B, 128, N1)
    const float* xyz0  = (const float*)d_in[4];   // (B, N0, 3)
    const float* xyz1  = (const float*)d_in[5];   // (B, N1, 3)
    const float* xyz2  = (const float*)d_in[6];   // (B, N2, 3)

    float* ws = (float*)d_ws;
    size_t off = 0;
    auto alloc = [&](size_t n) { size_t p = off; off += (n + 15) & ~(size_t)15; return p; };

    size_t f0b   = alloc((size_t)B * I2 * N0);    // adapter1 out (per-b)
    size_t f1b   = alloc((size_t)B * I1 * N1);    // adapter2 out (per-b)
    size_t wgt1  = alloc((size_t)B * N1 * 3);
    size_t wgt2  = alloc((size_t)B * N0 * 3);
    size_t idx1  = alloc((size_t)B * N1 * 3);
    size_t idx2  = alloc((size_t)B * N0 * 3);
    size_t slotA = alloc((size_t)NB * I2 * N0);   // h1 / interp1 / interp2
    size_t slotB = alloc((size_t)NB * I2 * N0);   // h2 / h3 / h5
    size_t slotC = alloc((size_t)NB * I3 * N0);   // h4 / h6
    (void)ws_size; (void)in_sizes; (void)n_in;

    auto conv = [&](const float* s0, int C0, int q0, const float* s1, int C1, int q1,
                    int wi, int bi, int bni, float* outp,
                    int O, int Nn, int nbatch, int relu) {
        dim3 grid((Nn + 255) / 256, (O + 15) / 16, nbatch);
        conv_bn_relu_kernel<<<grid, dim3(64, 4), 0, stream>>>(
            s0, C0, q0, s1, C1, q1,
            (const float*)d_in[wi], (const float*)d_in[bi],
            bni >= 0 ? (const float*)d_in[bni] : nullptr,
            outp, O, Nn, relu);
    };

    // adapters (per-b)
    conv(sa0f, 3, 1, nullptr, 0, 1, 13, 14, -1, ws + f0b, I2, N0, B, 0);
    conv(sa1f, 128, 1, nullptr, 0, 1, 15, 16, -1, ws + f1b, I1, N1, B, 0);

    // three_nn (per-b), segment-parallel
    three_nn_par_kernel<<<dim3(N1 / 32, B), dim3(512), 0, stream>>>(
        xyz1, xyz2, N1, N2, (int*)(ws + idx1), ws + wgt1);
    three_nn_par_kernel<<<dim3(N0 / 32, B), dim3(512), 0, stream>>>(
        xyz0, xyz1, N0, N1, (int*)(ws + idx2), ws + wgt2);

    // h1 = layer1(concat(x, mask)) : (NB, 296, 256) -> slotA
    conv(x, 288, Q, mask, 8, 1, 7, 8, 9, ws + slotA, 296, N2, NB, 1);
    // h2 = layer2(h1) : (NB, 144, 256) -> slotB
    conv(ws + slotA, 296, 1, nullptr, 0, 1, 10, 11, 12, ws + slotB, I1, N2, NB, 1);

    // interp1: h2 (Ns=256) -> (NB, 144, 1024) -> slotA
    interp_kernel<<<dim3(N1 / 256, I1, NB), dim3(256), 0, stream>>>(
        ws + slotB, (const int*)(ws + idx1), ws + wgt1, ws + slotA, I1, N2, N1, Q);

    // h3 = fp1_layer1(concat(interp1, f1)) -> slotB
    conv(ws + slotA, I1, 1, ws + f1b, I1, Q, 17, 18, 19, ws + slotB, I1, N1, NB, 1);
    // h4 = fp1_layer2(h3) -> slotC
    conv(ws + slotB, I1, 1, nullptr, 0, 1, 20, 21, 22, ws + slotC, I2, N1, NB, 1);

    // interp2: h4 (Ns=1024) -> (NB, 72, 4096) -> slotA
    interp_kernel<<<dim3(N0 / 256, I2, NB), dim3(256), 0, stream>>>(
        ws + slotC, (const int*)(ws + idx2), ws + wgt2, ws + slotA, I2, N1, N0, Q);

    // h5 = fp2_layer1(concat(interp2, f0)) -> slotB
    conv(ws + slotA, I2, 1, ws + f0b, I2, Q, 23, 24, 25, ws + slotB, I2, N0, NB, 1);
    // h6 = fp2_layer2(h5) -> slotC
    conv(ws + slotB, I2, 1, nullptr, 0, 1, 26, 27, 28, ws + slotC, I3, N0, NB, 1);

    // out = out_w @ h6 + out_b -> d_out (fp32)
    conv(ws + slotC, I3, 1, nullptr, 0, 1, 29, 30, -1, (float*)d_out, 1, N0, NB, 0);
}